// Round 4
// baseline (253.265 us; speedup 1.0000x reference)
//
#include <hip/hip_runtime.h>
#include <hip/hip_fp16.h>
#include <math.h>

#define NN    50000
#define NE0   800000
#define NE    850000
#define INDIM 128
#define HID   64
#define OUTD  40

#define NB    391          // ceil(50000/128) buckets of 128 dsts
#define BSH   7            // bucket shift (dst >> 7)
#define BCAP  4096         // per-bucket capacity (max load ~2330)

// ---------------------------------------------------------------- CSR build (fixed-capacity buckets, no global scan)
__global__ __launch_bounds__(512) void k_binit(int* __restrict__ bcur) {
    int i = threadIdx.x;
    if (i < NB) bcur[i] = i << 12;       // BCAP = 4096
}

// bin edges by bucket: block reserves per-bucket ranges via global atomics
__global__ __launch_bounds__(256) void k_bin(const int* __restrict__ ei,
                                             int* __restrict__ bcur,
                                             unsigned int* __restrict__ epack) {
    __shared__ int lh[NB];
    __shared__ int lbase[NB];
    const int tid = threadIdx.x;
    const int CH = (NE + 255) / 256;           // 3321
    const int e_begin = blockIdx.x * CH;
    const int e_end = (e_begin + CH < NE) ? e_begin + CH : NE;

    for (int i = tid; i < NB; i += 256) lh[i] = 0;
    __syncthreads();
    for (int e = e_begin + tid; e < e_end; e += 256) {
        int dst = (e < NE0) ? ei[NE0 + e] : (e - NE0);
        atomicAdd(&lh[dst >> BSH], 1);
    }
    __syncthreads();
    for (int i = tid; i < NB; i += 256) {
        int c = lh[i];
        lbase[i] = c ? atomicAdd(&bcur[i], c) : 0;
        lh[i] = 0;
    }
    __syncthreads();
    for (int e = e_begin + tid; e < e_end; e += 256) {
        int src, dst;
        if (e < NE0) { src = ei[e]; dst = ei[NE0 + e]; }
        else         { src = e - NE0; dst = src; }
        int bkt = dst >> BSH;
        int lpos = atomicAdd(&lh[bkt], 1);
        epack[lbase[bkt] + lpos] = (unsigned int)src | ((unsigned int)(dst & 127) << 16);
    }
}

// per-bucket fine CSR: LDS histogram over 128 dsts, scan, scatter (L2-local)
__global__ __launch_bounds__(256) void k_bucket_csr(
    const int* __restrict__ bcur, const unsigned int* __restrict__ epack,
    int* __restrict__ off_s, int* __restrict__ off_e, int* __restrict__ esrc) {
    __shared__ int lh[128];
    __shared__ int lcur[128];
    __shared__ int sblk;
    const int tid = threadIdx.x, lane = tid & 63;
    const int b = blockIdx.x;
    const int e0 = b << 12;
    const int cnt = bcur[b] - e0;

    if (tid < 128) lh[tid] = 0;
    __syncthreads();
    for (int i = tid; i < cnt; i += 256)
        atomicAdd(&lh[epack[e0 + i] >> 16], 1);
    __syncthreads();

    int v = 0, incl = 0;
    if (tid < 128) {
        v = lh[tid];
        incl = v;
#pragma unroll
        for (int s = 1; s < 64; s <<= 1) {
            int t = __shfl_up(incl, s);
            if (lane >= s) incl += t;
        }
    }
    if (tid == 63) sblk = incl;
    __syncthreads();
    if (tid >= 64 && tid < 128) incl += sblk;
    if (tid < 128) {
        int ex = e0 + incl - v;
        lcur[tid] = ex;
        int gd = b * 128 + tid;
        if (gd < NN) { off_s[gd] = ex; off_e[gd] = ex + v; }
    }
    __syncthreads();

    for (int i = tid; i < cnt; i += 256) {
        unsigned int p = epack[e0 + i];
        int pos = atomicAdd(&lcur[p >> 16], 1);
        esrc[pos] = (int)(p & 0xFFFFu);
    }
}

// ---------------------------------------------------------------- GEMM1: x(50000x128)@W1(128x64), 4x4 reg tile, fp16 h1 out
__global__ __launch_bounds__(256, 2) void k_gemm1(
    const float* __restrict__ x, const float* __restrict__ W1,
    const float* __restrict__ a_s, const float* __restrict__ a_d,
    __half* __restrict__ h1h, float* __restrict__ asrc1, float* __restrict__ adst1)
{
    __shared__ float Wl[INDIM * HID];      // 32 KB
    __shared__ float xs[64 * 132];         // 33.8 KB, padded stride 132
    const int tid = threadIdx.x;
    const int r0 = blockIdx.x * 64;

    const float4* W4 = (const float4*)W1;
    float4* Wl4 = (float4*)Wl;
#pragma unroll
    for (int i = 0; i < 8; ++i) Wl4[tid + i * 256] = W4[tid + i * 256];

    const float4* x4 = (const float4*)x;
#pragma unroll
    for (int i = 0; i < 8; ++i) {
        int idx = tid + i * 256;           // 0..2047
        int row = idx >> 5;                // 32 float4 per row
        int k4  = idx & 31;
        int nr = r0 + row;
        float4 v = make_float4(0.f, 0.f, 0.f, 0.f);
        if (nr < NN) v = x4[(size_t)nr * 32 + k4];
        *(float4*)&xs[row * 132 + k4 * 4] = v;
    }
    __syncthreads();

    const int rg = tid >> 4;               // 0..15 (4 rows each)
    const int cg = tid & 15;
    const int c4 = cg * 4;
    const float as0 = a_s[c4], as1v = a_s[c4+1], as2v = a_s[c4+2], as3v = a_s[c4+3];
    const float ad0 = a_d[c4], ad1v = a_d[c4+1], ad2v = a_d[c4+2], ad3v = a_d[c4+3];

    float acc[4][4];
#pragma unroll
    for (int i = 0; i < 4; ++i)
#pragma unroll
        for (int j = 0; j < 4; ++j) acc[i][j] = 0.f;

#pragma unroll 4
    for (int k4 = 0; k4 < 32; ++k4) {
        float4 xv[4];
#pragma unroll
        for (int i = 0; i < 4; ++i)
            xv[i] = *(const float4*)&xs[(rg * 4 + i) * 132 + k4 * 4];
        const float* wp = &Wl[(k4 * 4) * HID + c4];
        float4 w0 = *(const float4*)(wp);
        float4 w1 = *(const float4*)(wp + HID);
        float4 w2 = *(const float4*)(wp + 2 * HID);
        float4 w3 = *(const float4*)(wp + 3 * HID);
#pragma unroll
        for (int i = 0; i < 4; ++i) {
            acc[i][0] += xv[i].x * w0.x + xv[i].y * w1.x + xv[i].z * w2.x + xv[i].w * w3.x;
            acc[i][1] += xv[i].x * w0.y + xv[i].y * w1.y + xv[i].z * w2.y + xv[i].w * w3.y;
            acc[i][2] += xv[i].x * w0.z + xv[i].y * w1.z + xv[i].z * w2.z + xv[i].w * w3.z;
            acc[i][3] += xv[i].x * w0.w + xv[i].y * w1.w + xv[i].z * w2.w + xv[i].w * w3.w;
        }
    }

#pragma unroll
    for (int i = 0; i < 4; ++i) {
        const int n = r0 + rg * 4 + i;
        if (n < NN) {
            __half2 ha = __floats2half2_rn(acc[i][0], acc[i][1]);
            __half2 hb = __floats2half2_rn(acc[i][2], acc[i][3]);
            *(__half2*)&h1h[(size_t)n * HID + c4]     = ha;
            *(__half2*)&h1h[(size_t)n * HID + c4 + 2] = hb;
        }
        float ps = acc[i][0] * as0 + acc[i][1] * as1v + acc[i][2] * as2v + acc[i][3] * as3v;
        float pd = acc[i][0] * ad0 + acc[i][1] * ad1v + acc[i][2] * ad2v + acc[i][3] * ad3v;
        ps += __shfl_xor(ps, 1); ps += __shfl_xor(ps, 2);
        pd += __shfl_xor(pd, 1); pd += __shfl_xor(pd, 2);
        if ((cg & 3) == 0 && n < NN) {
            int head = cg >> 2;
            asrc1[n * 4 + head] = ps;
            adst1[n * 4 + head] = pd;
        }
    }
}

// ---------------------------------------------------------------- layer-1 single-pass aggregate + bias + relu
__global__ __launch_bounds__(256) void k_fagg1(
    const int* __restrict__ off_s, const int* __restrict__ off_e,
    const int* __restrict__ esrc,
    const __half* __restrict__ h1h, const float* __restrict__ asrc1,
    const float* __restrict__ adst1, const float* __restrict__ b1,
    float* __restrict__ hmid)
{
    const int wv = threadIdx.x >> 6, lane = threadIdx.x & 63;
    const int n = blockIdx.x * 4 + wv;
    if (n >= NN) return;
    const int s0 = off_s[n], s1 = off_e[n];
    const int hp = lane >> 4;
    const float adst = adst1[n * 4 + hp];

    float l = 0.f, acc = 0.f;
    int idx = s0;
    for (; idx + 3 < s1; idx += 4) {
        int sA = esrc[idx], sB = esrc[idx + 1], sC = esrc[idx + 2], sD = esrc[idx + 3];
        float eA = asrc1[sA * 4 + hp] + adst;
        float eB = asrc1[sB * 4 + hp] + adst;
        float eC = asrc1[sC * 4 + hp] + adst;
        float eD = asrc1[sD * 4 + hp] + adst;
        eA = (eA > 0.f) ? eA : 0.2f * eA;
        eB = (eB > 0.f) ? eB : 0.2f * eB;
        eC = (eC > 0.f) ? eC : 0.2f * eC;
        eD = (eD > 0.f) ? eD : 0.2f * eD;
        float hA = __half2float(h1h[(size_t)sA * HID + lane]);
        float hB = __half2float(h1h[(size_t)sB * HID + lane]);
        float hC = __half2float(h1h[(size_t)sC * HID + lane]);
        float hD = __half2float(h1h[(size_t)sD * HID + lane]);
        float wA = __expf(eA), wB = __expf(eB), wC = __expf(eC), wD = __expf(eD);
        l += wA + wB + wC + wD;
        acc += wA * hA + wB * hB + wC * hC + wD * hD;
    }
    for (; idx < s1; ++idx) {
        int s = esrc[idx];
        float e = asrc1[s * 4 + hp] + adst;
        e = (e > 0.f) ? e : 0.2f * e;
        float w = __expf(e);
        l += w;
        acc += w * __half2float(h1h[(size_t)s * HID + lane]);
    }
    float val = acc / l + b1[lane];
    hmid[(size_t)n * HID + lane] = fmaxf(val, 0.f);
}

// ---------------------------------------------------------------- GEMM2: hmid(50000x64) @ W2(64x40), fp16 h2 out
__global__ __launch_bounds__(320) void k_gemm2(
    const float* __restrict__ hin, const float* __restrict__ W2,
    const float* __restrict__ a_s, const float* __restrict__ a_d,
    __half* __restrict__ h2h, float* __restrict__ asrc2, float* __restrict__ adst2)
{
    __shared__ float Wl[HID * OUTD];       // 2560 floats
    __shared__ float xs[32 * 68];          // padded stride 68
    __shared__ float s_as[32], s_ad[32];
    const int tid = threadIdx.x;
    const int r0 = blockIdx.x * 32;

    const float4* W4 = (const float4*)W2;  // 640 float4
    float4* Wl4 = (float4*)Wl;
    for (int i = tid; i < 640; i += 320) Wl4[i] = W4[i];
    const float4* x4 = (const float4*)hin;
    for (int i = tid; i < 512; i += 320) {
        int row = i >> 4;                  // 16 float4 per row
        int k4  = i & 15;
        int nr = r0 + row;
        float4 v = make_float4(0.f, 0.f, 0.f, 0.f);
        if (nr < NN) v = x4[(size_t)nr * 16 + k4];
        *(float4*)&xs[row * 68 + k4 * 4] = v;
    }
    if (tid < 32) { s_as[tid] = 0.f; s_ad[tid] = 0.f; }
    __syncthreads();

    const int r  = tid / 10;               // 0..31
    const int cg = tid % 10;
    const int c4 = cg * 4;                 // 0..36
    float a0 = 0.f, a1 = 0.f, a2 = 0.f, a3 = 0.f;
#pragma unroll 4
    for (int k4 = 0; k4 < 16; ++k4) {
        float4 xv = *(const float4*)&xs[r * 68 + k4 * 4];
        const float* wp = &Wl[(k4 * 4) * OUTD + c4];
        float4 w0 = *(const float4*)(wp);
        float4 w1 = *(const float4*)(wp + OUTD);
        float4 w2 = *(const float4*)(wp + 2 * OUTD);
        float4 w3 = *(const float4*)(wp + 3 * OUTD);
        a0 += xv.x * w0.x + xv.y * w1.x + xv.z * w2.x + xv.w * w3.x;
        a1 += xv.x * w0.y + xv.y * w1.y + xv.z * w2.y + xv.w * w3.y;
        a2 += xv.x * w0.z + xv.y * w1.z + xv.z * w2.z + xv.w * w3.z;
        a3 += xv.x * w0.w + xv.y * w1.w + xv.z * w2.w + xv.w * w3.w;
    }
    const int n = r0 + r;
    float ps = a0 * a_s[c4] + a1 * a_s[c4 + 1] + a2 * a_s[c4 + 2] + a3 * a_s[c4 + 3];
    float pd = a0 * a_d[c4] + a1 * a_d[c4 + 1] + a2 * a_d[c4 + 2] + a3 * a_d[c4 + 3];
    atomicAdd(&s_as[r], ps);
    atomicAdd(&s_ad[r], pd);
    if (n < NN) {
        __half2 ha = __floats2half2_rn(a0, a1);
        __half2 hb = __floats2half2_rn(a2, a3);
        *(__half2*)&h2h[(size_t)n * OUTD + c4]     = ha;
        *(__half2*)&h2h[(size_t)n * OUTD + c4 + 2] = hb;
    }
    __syncthreads();
    if (tid < 32) {
        int n2 = r0 + tid;
        if (n2 < NN) { asrc2[n2] = s_as[tid]; adst2[n2] = s_ad[tid]; }
    }
}

// ---------------------------------------------------------------- layer-2 single-pass aggregate + bias + log_softmax
__global__ __launch_bounds__(256) void k_fagg2(
    const int* __restrict__ off_s, const int* __restrict__ off_e,
    const int* __restrict__ esrc,
    const __half* __restrict__ h2h, const float* __restrict__ asrc2,
    const float* __restrict__ adst2, const float* __restrict__ b2,
    float* __restrict__ out)
{
    const int wv = threadIdx.x >> 6, lane = threadIdx.x & 63;
    const int n = blockIdx.x * 4 + wv;
    if (n >= NN) return;
    const int s0 = off_s[n], s1 = off_e[n];
    const float adst = adst2[n];
    const bool act = lane < OUTD;

    float l = 0.f, acc = 0.f;
    int idx = s0;
    for (; idx + 3 < s1; idx += 4) {
        int sA = esrc[idx], sB = esrc[idx + 1], sC = esrc[idx + 2], sD = esrc[idx + 3];
        float eA = asrc2[sA] + adst, eB = asrc2[sB] + adst;
        float eC = asrc2[sC] + adst, eD = asrc2[sD] + adst;
        eA = (eA > 0.f) ? eA : 0.2f * eA;
        eB = (eB > 0.f) ? eB : 0.2f * eB;
        eC = (eC > 0.f) ? eC : 0.2f * eC;
        eD = (eD > 0.f) ? eD : 0.2f * eD;
        float hA = act ? __half2float(h2h[(size_t)sA * OUTD + lane]) : 0.f;
        float hB = act ? __half2float(h2h[(size_t)sB * OUTD + lane]) : 0.f;
        float hC = act ? __half2float(h2h[(size_t)sC * OUTD + lane]) : 0.f;
        float hD = act ? __half2float(h2h[(size_t)sD * OUTD + lane]) : 0.f;
        float wA = __expf(eA), wB = __expf(eB), wC = __expf(eC), wD = __expf(eD);
        l += wA + wB + wC + wD;
        acc += wA * hA + wB * hB + wC * hC + wD * hD;
    }
    for (; idx < s1; ++idx) {
        int s = esrc[idx];
        float e = asrc2[s] + adst;
        e = (e > 0.f) ? e : 0.2f * e;
        float w = __expf(e);
        float hv = act ? __half2float(h2h[(size_t)s * OUTD + lane]) : 0.f;
        l += w;
        acc += w * hv;
    }

    float val = act ? (acc / l + b2[lane]) : -1e30f;
    float mx = val;
#pragma unroll
    for (int o = 32; o; o >>= 1) mx = fmaxf(mx, __shfl_xor(mx, o));
    float ex = act ? __expf(val - mx) : 0.f;
    float sm = ex;
#pragma unroll
    for (int o = 32; o; o >>= 1) sm += __shfl_xor(sm, o);
    if (act) out[(size_t)n * OUTD + lane] = val - mx - __logf(sm);
}

// ----------------------------------------------------------------
extern "C" void kernel_launch(void* const* d_in, const int* in_sizes, int n_in,
                              void* d_out, int out_size, void* d_ws, size_t ws_size,
                              hipStream_t stream)
{
    const float* x   = (const float*)d_in[0];
    const int*   ei  = (const int*)  d_in[1];
    const float* W1  = (const float*)d_in[2];
    const float* as1 = (const float*)d_in[3];
    const float* ad1 = (const float*)d_in[4];
    const float* b1  = (const float*)d_in[5];
    const float* W2  = (const float*)d_in[6];
    const float* as2 = (const float*)d_in[7];
    const float* ad2 = (const float*)d_in[8];
    const float* b2  = (const float*)d_in[9];
    float* out = (float*)d_out;

    char* ws = (char*)d_ws;
    __half* h1h   = (__half*)(ws);                        //  6,400,000 B
    float*  hmid  = (float*) (ws + 6400000);              // 12,800,000 B
    __half* h2h   = (__half*)(ws + 19200000);             //  4,000,000 B
    float*  asrc1 = (float*) (ws + 23200000);             //    800,000 B
    float*  adst1 = (float*) (ws + 24000000);             //    800,000 B
    float*  asrc2 = (float*) (ws + 24800000);             //    200,000 B
    float*  adst2 = (float*) (ws + 25000000);             //    200,000 B
    int*    off_s = (int*)   (ws + 25200000);             //    200,000 B
    int*    off_e = (int*)   (ws + 25400000);             //    200,000 B
    int*    esrc  = (int*)   (ws + 25600000);             //  6,406,144 B (NB*BCAP*4)
    unsigned int* epack = (unsigned int*)(ws + 32006144); //  6,406,144 B
    int*    bcur  = (int*)   (ws + 38412288);             //      1,564 B

    hipLaunchKernelGGL(k_binit,      dim3(1),    dim3(512), 0, stream, bcur);
    hipLaunchKernelGGL(k_bin,        dim3(256),  dim3(256), 0, stream, ei, bcur, epack);
    hipLaunchKernelGGL(k_bucket_csr, dim3(NB),   dim3(256), 0, stream, bcur, epack, off_s, off_e, esrc);
    hipLaunchKernelGGL(k_gemm1,      dim3(782),  dim3(256), 0, stream, x, W1, as1, ad1, h1h, asrc1, adst1);
    hipLaunchKernelGGL(k_fagg1,      dim3(12500),dim3(256), 0, stream, off_s, off_e, esrc, h1h, asrc1, adst1, b1, hmid);
    hipLaunchKernelGGL(k_gemm2,      dim3(1563), dim3(320), 0, stream, hmid, W2, as2, ad2, h2h, asrc2, adst2);
    hipLaunchKernelGGL(k_fagg2,      dim3(12500),dim3(256), 0, stream, off_s, off_e, esrc, h2h, asrc2, adst2, b2, out);
}